// Round 1
// baseline (289.443 us; speedup 1.0000x reference)
//
#include <hip/hip_runtime.h>
#include <math.h>

#define NB 128
#define DHH 512
#define MM 4096
#define DD 128
#define EPSV 1e-8f

// d_out layout (floats)
#define HO_OFF   0
#define CN_OFF   65536
#define K_OFF    67174400
#define R_OFF    67190784
// scratch in tail of C_new region (all consumed before passC overwrites)
#define TAIL_OFF 65863680
// tail-relative offsets
#define CN2_T    0
#define GH_T     524288
#define GI_T     720896
#define BETA_T   917504
#define PR_T     917632
// ws layout (floats): w buffer, e, v  (must survive into passC)
#define W_WS     0
#define E_WS     524288
#define V_WS     540672

struct Seg { int jend; const float* W; const float* B; float* dst; int stride; int act; };

__device__ __forceinline__ float sigm(float x){ return 1.0f/(1.0f+expf(-x)); }

// Generic small-GEMM: out[n, j] = act( X[n,:K] . W[j,:K] + B[j] ), 8 j's per block.
template<int K>
__global__ __launch_bounds__(512) void proj8(const float* __restrict__ X, Seg s0, Seg s1, Seg s2)
{
    __shared__ float wlds[8][K];
    __shared__ float red[4][128][9];
    int t = threadIdx.x;
    int jbase = blockIdx.x * 8;
    for (int idx = t; idx < 8*K; idx += 512){
        int jj = idx / K, kk = idx - jj*K;
        int j = jbase + jj;
        const float* wrow = nullptr;
        if (j < s0.jend) wrow = s0.W + (size_t)j * K;
        else if (j < s1.jend) wrow = s1.W + (size_t)(j - s0.jend) * K;
        else if (j < s2.jend) wrow = s2.W + (size_t)(j - s1.jend) * K;
        wlds[jj][kk] = wrow ? wrow[kk] : 0.0f;
    }
    __syncthreads();
    {
        int n = t & 127, q = t >> 7;
        const int KQ = K/4;
        float acc[8];
        #pragma unroll
        for (int jj=0;jj<8;jj++) acc[jj]=0.0f;
        const float* xrow = X + (size_t)n*K + q*KQ;
        const float* wq = &wlds[0][0] + q*KQ;
        for (int kk=0; kk<KQ; ++kk){
            float xv = xrow[kk];
            #pragma unroll
            for (int jj=0;jj<8;jj++) acc[jj] = fmaf(xv, wq[jj*K+kk], acc[jj]);
        }
        #pragma unroll
        for (int jj=0;jj<8;jj++) red[q][n][jj] = acc[jj];
    }
    __syncthreads();
    if (t < 128){
        #pragma unroll
        for (int jj=0;jj<8;jj++){
            int j = jbase + jj;
            const Seg* sg = nullptr; int loc = 0;
            if (j < s0.jend){ sg=&s0; loc=j; }
            else if (j < s1.jend){ sg=&s1; loc=j-s0.jend; }
            else if (j < s2.jend){ sg=&s2; loc=j-s1.jend; }
            if (sg){
                float v = red[0][t][jj]+red[1][t][jj]+red[2][t][jj]+red[3][t][jj] + sg->B[loc];
                if (sg->act==1) v = sigm(v);
                sg->dst[(size_t)t * sg->stride + loc] = v;
            }
        }
    }
}

// Pass A: dots[n,m] = C[n,m,:].k[n,:], cn2[n,m] = ||C[n,m,:]||^2. 16 lanes per row.
__global__ __launch_bounds__(256) void passA(const float* __restrict__ C, const float* __restrict__ kv,
                                             float* __restrict__ dots, float* __restrict__ cn2)
{
    __shared__ float kl[128];
    int t = threadIdx.x;
    int n = blockIdx.x >> 6;
    int mbase = (blockIdx.x & 63) << 6;
    if (t < 128) kl[t] = kv[n*DD + t];
    __syncthreads();
    int s = t & 15, rowg = t >> 4;
    const float4* kl4 = (const float4*)kl;
    float4 ka = kl4[s*2], kb = kl4[s*2+1];
    const float4* C4 = (const float4*)C;
    #pragma unroll
    for (int it=0; it<4; ++it){
        int m = mbase + it*16 + rowg;
        size_t ridx = ((size_t)n*MM + m)*32 + s*2;
        float4 a = C4[ridx], b = C4[ridx+1];
        float dot = a.x*ka.x + a.y*ka.y + a.z*ka.z + a.w*ka.w
                  + b.x*kb.x + b.y*kb.y + b.z*kb.z + b.w*kb.w;
        float nr  = a.x*a.x + a.y*a.y + a.z*a.z + a.w*a.w
                  + b.x*b.x + b.y*b.y + b.z*b.z + b.w*b.w;
        #pragma unroll
        for (int off=1; off<16; off<<=1){
            dot += __shfl_xor(dot, off);
            nr  += __shfl_xor(nr, off);
        }
        if (s == 0){
            dots[(size_t)n*MM + m] = dot;
            cn2 [(size_t)n*MM + m] = nr;
        }
    }
}

// Softmax over m per n: w = softmax(beta * dots / max(cnorm*knorm, eps)); in-place over dots buf.
__global__ __launch_bounds__(256) void softmax_k(float* __restrict__ wbuf, const float* __restrict__ cn2,
                                                 const float* __restrict__ kv, const float* __restrict__ beta_raw)
{
    __shared__ float red[256];
    __shared__ float s_kn, s_beta;
    int n = blockIdx.x, t = threadIdx.x;
    float kq = 0.0f;
    if (t < 128){ float x = kv[n*DD + t]; kq = x*x; }
    red[t] = kq; __syncthreads();
    for (int off=128; off>0; off>>=1){ if (t<off) red[t]+=red[t+off]; __syncthreads(); }
    if (t==0){
        s_kn = sqrtf(red[0]);
        float b = beta_raw[n];
        float sp = fmaxf(b, 0.0f) + log1pf(expf(-fabsf(b)));
        s_beta = 1.0f + sp;
    }
    __syncthreads();
    float knorm = s_kn, beta = s_beta;
    float sv[16];
    float mx = -INFINITY;
    float* wrow = wbuf + (size_t)n*MM;
    const float* crow = cn2 + (size_t)n*MM;
    #pragma unroll
    for (int i=0;i<16;i++){
        int m = t + i*256;
        float dot = wrow[m];
        float cn = sqrtf(crow[m]);
        float s = beta * dot / fmaxf(cn*knorm, EPSV);
        sv[i] = s; mx = fmaxf(mx, s);
    }
    __syncthreads();
    red[t] = mx; __syncthreads();
    for (int off=128; off>0; off>>=1){ if (t<off) red[t]=fmaxf(red[t],red[t+off]); __syncthreads(); }
    mx = red[0];
    __syncthreads();
    float sum = 0.0f;
    #pragma unroll
    for (int i=0;i<16;i++){ sv[i] = expf(sv[i]-mx); sum += sv[i]; }
    red[t] = sum; __syncthreads();
    for (int off=128; off>0; off>>=1){ if (t<off) red[t]+=red[t+off]; __syncthreads(); }
    float inv = 1.0f / red[0];
    #pragma unroll
    for (int i=0;i<16;i++) wrow[t + i*256] = sv[i]*inv;
}

// Pass B1: partial r over m-chunks of 512.
__global__ __launch_bounds__(256) void passB1(const float* __restrict__ C, const float* __restrict__ w,
                                              float* __restrict__ pr)
{
    int t = threadIdx.x;
    int n = blockIdx.x >> 3, chunk = blockIdx.x & 7;
    int l = t & 63, g = t >> 6;
    const float2* C2 = (const float2*)C;
    const float* wrow = w + (size_t)n*MM + chunk*512;
    float2 acc; acc.x = 0.0f; acc.y = 0.0f;
    for (int mm = g; mm < 512; mm += 4){
        int m = chunk*512 + mm;
        float wm = wrow[mm];
        float2 c = C2[((size_t)n*MM + m)*64 + l];
        acc.x = fmaf(wm, c.x, acc.x);
        acc.y = fmaf(wm, c.y, acc.y);
    }
    __shared__ float2 red[256];
    red[t] = acc; __syncthreads();
    if (t < 64){
        float2 a=red[t], b=red[t+64], c=red[t+128], d=red[t+192];
        float2 tot; tot.x = a.x+b.x+c.x+d.x; tot.y = a.y+b.y+c.y+d.y;
        ((float2*)pr)[((size_t)n*8 + chunk)*64 + t] = tot;
    }
}

__global__ void passB2(const float* __restrict__ pr, float* __restrict__ r_out)
{
    int t = threadIdx.x, n = blockIdx.x;
    float s = 0.0f;
    for (int c=0;c<8;c++) s += pr[((size_t)n*8 + c)*DD + t];
    r_out[n*DD + t] = s;
}

// GRU gates: h' = (1-z)*tanh(gi_n + rg*gh_n) + z*h
__global__ __launch_bounds__(256) void gates_k(const float* __restrict__ gi, const float* __restrict__ gh,
                                               const float* __restrict__ hp, float* __restrict__ ho)
{
    int idx = blockIdx.x*256 + threadIdx.x;
    int n = idx >> 9, j = idx & 511;
    const float* gir = gi + (size_t)n*1536;
    const float* ghr = gh + (size_t)n*1536;
    float rg = sigm(gir[j] + ghr[j]);
    float z  = sigm(gir[512+j] + ghr[512+j]);
    float ng = tanhf(gir[1024+j] + rg*ghr[1024+j]);
    float h  = hp[idx];
    ho[idx] = (1.0f - z)*ng + z*h;
}

// Pass C: C_new = C*(1 - w*e) + w*v
__global__ __launch_bounds__(256) void passC(const float* __restrict__ C, const float* __restrict__ w,
                                             const float* __restrict__ e, const float* __restrict__ v,
                                             float* __restrict__ Cn)
{
    int t = threadIdx.x;
    int n = blockIdx.x >> 6, mbase = (blockIdx.x & 63) << 6;
    int l = t & 31, q = t >> 5;
    float4 e4 = ((const float4*)(e + (size_t)n*DD))[l];
    float4 v4 = ((const float4*)(v + (size_t)n*DD))[l];
    const float4* C4 = (const float4*)C;
    float4* Cn4 = (float4*)Cn;
    const float* wrow = w + (size_t)n*MM;
    #pragma unroll
    for (int it=0; it<8; ++it){
        int m = mbase + it*8 + q;
        float wm = wrow[m];
        size_t ridx = ((size_t)n*MM + m)*32 + l;
        float4 c = C4[ridx];
        float4 o;
        o.x = fmaf(wm, v4.x, c.x * (1.0f - wm*e4.x));
        o.y = fmaf(wm, v4.y, c.y * (1.0f - wm*e4.y));
        o.z = fmaf(wm, v4.z, c.z * (1.0f - wm*e4.z));
        o.w = fmaf(wm, v4.w, c.w * (1.0f - wm*e4.w));
        Cn4[ridx] = o;
    }
}

extern "C" void kernel_launch(void* const* d_in, const int* in_sizes, int n_in,
                              void* d_out, int out_size, void* d_ws, size_t ws_size,
                              hipStream_t stream) {
    const float* hp   = (const float*)d_in[0];
    const float* C    = (const float*)d_in[1];
    const float* Wk   = (const float*)d_in[2];
    const float* bk   = (const float*)d_in[3];
    const float* Wb   = (const float*)d_in[4];
    const float* bb   = (const float*)d_in[5];
    const float* We   = (const float*)d_in[6];
    const float* be   = (const float*)d_in[7];
    const float* Wv   = (const float*)d_in[8];
    const float* bv   = (const float*)d_in[9];
    const float* W_ih = (const float*)d_in[10];
    const float* b_ih = (const float*)d_in[11];
    const float* W_hh = (const float*)d_in[12];
    const float* b_hh = (const float*)d_in[13];

    float* out   = (float*)d_out;
    float* ho    = out + HO_OFF;
    float* Cn    = out + CN_OFF;
    float* k_out = out + K_OFF;
    float* r_out = out + R_OFF;

    float* tail  = out + TAIL_OFF;
    float* cn2   = tail + CN2_T;
    float* gh    = tail + GH_T;
    float* gi    = tail + GI_T;
    float* braw  = tail + BETA_T;
    float* pr    = tail + PR_T;

    float* wsf = (float*)d_ws;
    float* wbuf = wsf + W_WS;
    float* ebuf = wsf + E_WS;
    float* vbuf = wsf + V_WS;

    // 1) k, gh, beta_pre  (from h_o_prev, K=512)
    {
        Seg s0 = {128, Wk, bk, k_out, 128, 0};
        Seg s1 = {1664, W_hh, b_hh, gh, 1536, 0};
        Seg s2 = {1665, Wb, bb, braw, 1, 0};
        proj8<512><<<209, 512, 0, stream>>>(hp, s0, s1, s2);
    }
    // 2) dots + C-norms
    passA<<<8192, 256, 0, stream>>>(C, k_out, wbuf, cn2);
    // 3) softmax -> w (in place)
    softmax_k<<<128, 256, 0, stream>>>(wbuf, cn2, k_out, braw);
    // 4) r = sum_m w*C
    passB1<<<1024, 256, 0, stream>>>(C, wbuf, pr);
    passB2<<<128, 128, 0, stream>>>(pr, r_out);
    // 5) gi = r @ W_ih^T + b_ih  (K=128)
    {
        Seg s0 = {1536, W_ih, b_ih, gi, 1536, 0};
        Seg s1 = {1536, nullptr, nullptr, nullptr, 0, 0};
        Seg s2 = {1536, nullptr, nullptr, nullptr, 0, 0};
        proj8<128><<<192, 512, 0, stream>>>(r_out, s0, s1, s2);
    }
    // 6) GRU gates -> h_o
    gates_k<<<256, 256, 0, stream>>>(gi, gh, hp, ho);
    // 7) e = sigmoid(h@We^T+be), v = h@Wv^T+bv  (K=512)
    {
        Seg s0 = {128, We, be, ebuf, 128, 1};
        Seg s1 = {256, Wv, bv, vbuf, 128, 0};
        Seg s2 = {256, nullptr, nullptr, nullptr, 0, 0};
        proj8<512><<<32, 512, 0, stream>>>(ho, s0, s1, s2);
    }
    // 8) C_new
    passC<<<8192, 256, 0, stream>>>(C, wbuf, ebuf, vbuf, Cn);
}

// Round 2
// 231.373 us; speedup vs baseline: 1.2510x; 1.2510x over previous
//
#include <hip/hip_runtime.h>
#include <math.h>

#define NB 128
#define DHH 512
#define MM 4096
#define DD 128
#define EPSV 1e-8f

// d_out layout (floats)
#define HO_OFF   0
#define CN_OFF   65536
#define K_OFF    67174400
#define R_OFF    67190784
// scratch inside C_new region (all consumed before passC overwrites it)
#define RACC_OFF  65536
#define LMAX_OFF  1114112
#define LSUM_OFF  1122304
#define GH_OFF    1130496
#define GI_OFF    1327104
#define BRAW_OFF  1523712
#define KNB_OFF   1523840
// ws layout (floats): these must survive into passC
#define S_WS     0
#define E_WS     524288
#define V_WS     540672
#define GZ_WS    557056

struct Seg { int jend; const float* W; const float* B; float* dst; int stride; int act; };

__device__ __forceinline__ float sigm(float x){ return 1.0f/(1.0f+expf(-x)); }

// Generic small-GEMM: out[n, j] = act( X[n,:K] . W[j,:K] + B[j] ), 8 j's per block.
template<int K>
__global__ __launch_bounds__(512) void proj8(const float* __restrict__ X, Seg s0, Seg s1, Seg s2)
{
    __shared__ float wlds[8][K];
    __shared__ float red[4][128][9];
    int t = threadIdx.x;
    int jbase = blockIdx.x * 8;
    for (int idx = t; idx < 8*K; idx += 512){
        int jj = idx / K, kk = idx - jj*K;
        int j = jbase + jj;
        const float* wrow = nullptr;
        if (j < s0.jend) wrow = s0.W + (size_t)j * K;
        else if (j < s1.jend) wrow = s1.W + (size_t)(j - s0.jend) * K;
        else if (j < s2.jend) wrow = s2.W + (size_t)(j - s1.jend) * K;
        wlds[jj][kk] = wrow ? wrow[kk] : 0.0f;
    }
    __syncthreads();
    {
        int n = t & 127, q = t >> 7;
        const int KQ = K/4;
        float acc[8];
        #pragma unroll
        for (int jj=0;jj<8;jj++) acc[jj]=0.0f;
        const float* xrow = X + (size_t)n*K + q*KQ;
        const float* wq = &wlds[0][0] + q*KQ;
        for (int kk=0; kk<KQ; ++kk){
            float xv = xrow[kk];
            #pragma unroll
            for (int jj=0;jj<8;jj++) acc[jj] = fmaf(xv, wq[jj*K+kk], acc[jj]);
        }
        #pragma unroll
        for (int jj=0;jj<8;jj++) red[q][n][jj] = acc[jj];
    }
    __syncthreads();
    if (t < 128){
        #pragma unroll
        for (int jj=0;jj<8;jj++){
            int j = jbase + jj;
            const Seg* sg = nullptr; int loc = 0;
            if (j < s0.jend){ sg=&s0; loc=j; }
            else if (j < s1.jend){ sg=&s1; loc=j-s0.jend; }
            else if (j < s2.jend){ sg=&s2; loc=j-s1.jend; }
            if (sg){
                float v = red[0][t][jj]+red[1][t][jj]+red[2][t][jj]+red[3][t][jj] + sg->B[loc];
                if (sg->act==1) v = sigm(v);
                sg->dst[(size_t)t * sg->stride + loc] = v;
            }
        }
    }
}

// knorm + beta per n
__global__ __launch_bounds__(128) void prep(const float* __restrict__ k, const float* __restrict__ braw,
                                            float* __restrict__ knb)
{
    __shared__ float red[128];
    int n = blockIdx.x, t = threadIdx.x;
    float x = k[n*DD + t];
    red[t] = x*x; __syncthreads();
    for (int off=64; off>0; off>>=1){ if (t<off) red[t]+=red[t+off]; __syncthreads(); }
    if (t==0) knb[n] = sqrtf(red[0]);
    if (t==1){
        float b = braw[n];
        knb[128+n] = 1.0f + fmaxf(b, 0.0f) + log1pf(expf(-fabsf(b)));
    }
}

// Fused pass A+B: per (n, 64-m chunk): scores s -> sbuf; online-softmax partials
// (lmax, lsum, racc[128] = sum exp(s-lmax)*C[m,:]) with C rows held in registers.
__global__ __launch_bounds__(256) void passAB(const float* __restrict__ C, const float* __restrict__ kv,
                                              const float* __restrict__ knb,
                                              float* __restrict__ sbuf, float* __restrict__ racc,
                                              float* __restrict__ lmaxb, float* __restrict__ lsumb)
{
    __shared__ float kl[128];
    __shared__ float red[256];
    __shared__ float rlds[16][136];
    int t = threadIdx.x;
    int n = blockIdx.x >> 6;
    int mbase = (blockIdx.x & 63) << 6;
    if (t < 128) kl[t] = kv[n*DD + t];
    __syncthreads();
    float knorm = knb[n];
    float beta  = knb[128+n];
    int s = t & 15, rowg = t >> 4;
    const float4* kl4 = (const float4*)kl;
    float4 ka = kl4[s*2], kb = kl4[s*2+1];
    const float4* C4 = (const float4*)C;
    float4 av[4], bw[4];
    float sval[4];
    #pragma unroll
    for (int it=0; it<4; ++it){
        int m = mbase + it*16 + rowg;
        size_t ridx = ((size_t)n*MM + m)*32 + s*2;
        float4 a = C4[ridx], b = C4[ridx+1];
        av[it] = a; bw[it] = b;
        float dot = a.x*ka.x + a.y*ka.y + a.z*ka.z + a.w*ka.w
                  + b.x*kb.x + b.y*kb.y + b.z*kb.z + b.w*kb.w;
        float nr  = a.x*a.x + a.y*a.y + a.z*a.z + a.w*a.w
                  + b.x*b.x + b.y*b.y + b.z*b.z + b.w*b.w;
        #pragma unroll
        for (int off=1; off<16; off<<=1){
            dot += __shfl_xor(dot, off);
            nr  += __shfl_xor(nr, off);
        }
        float cn = sqrtf(nr);
        float sv = beta * dot / fmaxf(cn*knorm, EPSV);
        sval[it] = sv;
        if (s == 0) sbuf[(size_t)n*MM + m] = sv;
    }
    // block-wide max over the 64 rows (values duplicated across 16 lanes -> max unaffected)
    float lm = fmaxf(fmaxf(sval[0],sval[1]), fmaxf(sval[2],sval[3]));
    red[t] = lm; __syncthreads();
    for (int off=128; off>0; off>>=1){ if (t<off) red[t]=fmaxf(red[t],red[t+off]); __syncthreads(); }
    float lmax = red[0];
    __syncthreads();
    // p = exp(s-lmax); accumulate racc slice + row-sum
    float r8[8] = {0,0,0,0,0,0,0,0};
    float ps = 0.0f;
    #pragma unroll
    for (int it=0; it<4; ++it){
        float p = expf(sval[it] - lmax);
        ps += p;
        r8[0] = fmaf(p, av[it].x, r8[0]); r8[1] = fmaf(p, av[it].y, r8[1]);
        r8[2] = fmaf(p, av[it].z, r8[2]); r8[3] = fmaf(p, av[it].w, r8[3]);
        r8[4] = fmaf(p, bw[it].x, r8[4]); r8[5] = fmaf(p, bw[it].y, r8[5]);
        r8[6] = fmaf(p, bw[it].z, r8[6]); r8[7] = fmaf(p, bw[it].w, r8[7]);
    }
    red[t] = (s==0) ? ps : 0.0f; __syncthreads();
    for (int off=128; off>0; off>>=1){ if (t<off) red[t]+=red[t+off]; __syncthreads(); }
    // reduce racc across the 16 row-groups
    #pragma unroll
    for (int j=0;j<8;j++) rlds[rowg][s*8+j] = r8[j];
    __syncthreads();
    for (int off=8; off>0; off>>=1){
        if (rowg < off){
            #pragma unroll
            for (int j=0;j<8;j++) rlds[rowg][s*8+j] += rlds[rowg+off][s*8+j];
        }
        __syncthreads();
    }
    if (rowg == 0){
        #pragma unroll
        for (int j=0;j<8;j++) racc[(size_t)blockIdx.x*128 + s*8+j] = rlds[0][s*8+j];
    }
    if (t == 0){ lmaxb[blockIdx.x] = lmax; lsumb[blockIdx.x] = red[0]; }
}

// Combine chunk partials -> r, gmax, 1/Z
__global__ __launch_bounds__(128) void combine(const float* __restrict__ racc, const float* __restrict__ lmaxb,
                                               const float* __restrict__ lsumb, float* __restrict__ r_out,
                                               float* __restrict__ gz)
{
    __shared__ float red[128];
    __shared__ float alpha[64];
    int n = blockIdx.x, t = threadIdx.x;
    float lm = (t < 64) ? lmaxb[n*64 + t] : -INFINITY;
    red[t] = lm; __syncthreads();
    for (int off=64; off>0; off>>=1){ if (t<off) red[t]=fmaxf(red[t],red[t+off]); __syncthreads(); }
    float gmax = red[0]; __syncthreads();
    float zc = 0.0f;
    if (t < 64){
        float a = expf(lmaxb[n*64 + t] - gmax);
        alpha[t] = a;
        zc = a * lsumb[n*64 + t];
    }
    red[t] = zc; __syncthreads();
    for (int off=64; off>0; off>>=1){ if (t<off) red[t]+=red[t+off]; __syncthreads(); }
    float Z = red[0];
    __syncthreads();
    float acc = 0.0f;
    const float* rb = racc + (size_t)n*64*128;
    for (int c=0; c<64; c++) acc = fmaf(alpha[c], rb[c*128 + t], acc);
    r_out[n*DD + t] = acc / Z;
    if (t == 0){ gz[n] = gmax; gz[128+n] = 1.0f/Z; }
}

// GRU gates: h' = (1-z)*tanh(gi_n + rg*gh_n) + z*h
__global__ __launch_bounds__(256) void gates_k(const float* __restrict__ gi, const float* __restrict__ gh,
                                               const float* __restrict__ hp, float* __restrict__ ho)
{
    int idx = blockIdx.x*256 + threadIdx.x;
    int n = idx >> 9, j = idx & 511;
    const float* gir = gi + (size_t)n*1536;
    const float* ghr = gh + (size_t)n*1536;
    float rg = sigm(gir[j] + ghr[j]);
    float z  = sigm(gir[512+j] + ghr[512+j]);
    float ng = tanhf(gir[1024+j] + rg*ghr[1024+j]);
    float h  = hp[idx];
    ho[idx] = (1.0f - z)*ng + z*h;
}

// Pass C: C_new = C*(1 - w*e) + w*v, with w = exp(s - gmax)/Z reconstructed on the fly
__global__ __launch_bounds__(256) void passC(const float* __restrict__ C, const float* __restrict__ sbuf,
                                             const float* __restrict__ gz,
                                             const float* __restrict__ e, const float* __restrict__ v,
                                             float* __restrict__ Cn)
{
    __shared__ float wl[64];
    int t = threadIdx.x;
    int n = blockIdx.x >> 6, mbase = (blockIdx.x & 63) << 6;
    if (t < 64){
        float gm = gz[n], iz = gz[128+n];
        wl[t] = expf(sbuf[(size_t)n*MM + mbase + t] - gm) * iz;
    }
    __syncthreads();
    int l = t & 31, q = t >> 5;
    float4 e4 = ((const float4*)(e + (size_t)n*DD))[l];
    float4 v4 = ((const float4*)(v + (size_t)n*DD))[l];
    const float4* C4 = (const float4*)C;
    float4* Cn4 = (float4*)Cn;
    #pragma unroll
    for (int it=0; it<8; ++it){
        int m = mbase + it*8 + q;
        float wm = wl[it*8 + q];
        size_t ridx = ((size_t)n*MM + m)*32 + l;
        float4 c = C4[ridx];
        float4 o;
        o.x = fmaf(wm, v4.x, c.x * (1.0f - wm*e4.x));
        o.y = fmaf(wm, v4.y, c.y * (1.0f - wm*e4.y));
        o.z = fmaf(wm, v4.z, c.z * (1.0f - wm*e4.z));
        o.w = fmaf(wm, v4.w, c.w * (1.0f - wm*e4.w));
        Cn4[ridx] = o;
    }
}

extern "C" void kernel_launch(void* const* d_in, const int* in_sizes, int n_in,
                              void* d_out, int out_size, void* d_ws, size_t ws_size,
                              hipStream_t stream) {
    const float* hp   = (const float*)d_in[0];
    const float* C    = (const float*)d_in[1];
    const float* Wk   = (const float*)d_in[2];
    const float* bk   = (const float*)d_in[3];
    const float* Wb   = (const float*)d_in[4];
    const float* bb   = (const float*)d_in[5];
    const float* We   = (const float*)d_in[6];
    const float* be   = (const float*)d_in[7];
    const float* Wv   = (const float*)d_in[8];
    const float* bv   = (const float*)d_in[9];
    const float* W_ih = (const float*)d_in[10];
    const float* b_ih = (const float*)d_in[11];
    const float* W_hh = (const float*)d_in[12];
    const float* b_hh = (const float*)d_in[13];

    float* out   = (float*)d_out;
    float* ho    = out + HO_OFF;
    float* Cn    = out + CN_OFF;
    float* k_out = out + K_OFF;
    float* r_out = out + R_OFF;

    // scratch inside C_new region (consumed before passC)
    float* racc  = out + RACC_OFF;
    float* lmaxb = out + LMAX_OFF;
    float* lsumb = out + LSUM_OFF;
    float* gh    = out + GH_OFF;
    float* gi    = out + GI_OFF;
    float* braw  = out + BRAW_OFF;
    float* knb   = out + KNB_OFF;

    float* wsf  = (float*)d_ws;
    float* sbuf = wsf + S_WS;
    float* ebuf = wsf + E_WS;
    float* vbuf = wsf + V_WS;
    float* gz   = wsf + GZ_WS;

    // 1) k, gh, beta_pre (from h_o_prev, K=512)
    {
        Seg s0 = {128, Wk, bk, k_out, 128, 0};
        Seg s1 = {1664, W_hh, b_hh, gh, 1536, 0};
        Seg s2 = {1665, Wb, bb, braw, 1, 0};
        proj8<512><<<209, 512, 0, stream>>>(hp, s0, s1, s2);
    }
    // 2) knorm + beta
    prep<<<128, 128, 0, stream>>>(k_out, braw, knb);
    // 3) fused scores + online-softmax partial r
    passAB<<<8192, 256, 0, stream>>>(C, k_out, knb, sbuf, racc, lmaxb, lsumb);
    // 4) combine -> r, gmax, 1/Z
    combine<<<128, 128, 0, stream>>>(racc, lmaxb, lsumb, r_out, gz);
    // 5) gi = r @ W_ih^T + b_ih  (K=128)
    {
        Seg s0 = {1536, W_ih, b_ih, gi, 1536, 0};
        Seg s1 = {1536, nullptr, nullptr, nullptr, 0, 0};
        Seg s2 = {1536, nullptr, nullptr, nullptr, 0, 0};
        proj8<128><<<192, 512, 0, stream>>>(r_out, s0, s1, s2);
    }
    // 6) GRU gates -> h_o
    gates_k<<<256, 256, 0, stream>>>(gi, gh, hp, ho);
    // 7) e = sigmoid(h@We^T+be), v = h@Wv^T+bv  (K=512)
    {
        Seg s0 = {128, We, be, ebuf, 128, 1};
        Seg s1 = {256, Wv, bv, vbuf, 128, 0};
        Seg s2 = {256, nullptr, nullptr, nullptr, 0, 0};
        proj8<512><<<32, 512, 0, stream>>>(ho, s0, s1, s2);
    }
    // 8) C_new = C*(1 - w*e) + w*v
    passC<<<8192, 256, 0, stream>>>(C, sbuf, gz, ebuf, vbuf, Cn);
}

// Round 4
// 195.211 us; speedup vs baseline: 1.4827x; 1.1852x over previous
//
#include <hip/hip_runtime.h>
#include <math.h>

#define NB 128
#define DHH 512
#define MM 4096
#define DD 128
#define EPSV 1e-8f

typedef float f32x4 __attribute__((ext_vector_type(4)));

// d_out layout (floats)
#define HO_OFF   0
#define CN_OFF   65536
#define K_OFF    67174400
#define R_OFF    67190784
// scratch inside C_new region (all consumed by `mid` before passC overwrites it)
#define RACC_OFF  65536
#define LMAX_OFF  1114112
#define LSUM_OFF  1122304
#define GH_OFF    1130496
#define BRAW_OFF  1327104
// ws layout (floats): these must survive into passC
#define S_WS     0
#define E_WS     524288
#define V_WS     540672
#define GZ_WS    557056

struct Seg { int jend; const float* W; const float* B; float* dst; int stride; int act; };

__device__ __forceinline__ float sigm(float x){ return 1.0f/(1.0f+expf(-x)); }

// Generic small-GEMM: out[n, j] = act( X[n,:K] . W[j,:K] + B[j] ), 8 j's per block.
template<int K>
__global__ __launch_bounds__(512) void proj8(const float* __restrict__ X, Seg s0, Seg s1, Seg s2)
{
    __shared__ float wlds[8][K];
    __shared__ float red[4][128][9];
    int t = threadIdx.x;
    int jbase = blockIdx.x * 8;
    for (int idx = t; idx < 8*K; idx += 512){
        int jj = idx / K, kk = idx - jj*K;
        int j = jbase + jj;
        const float* wrow = nullptr;
        if (j < s0.jend) wrow = s0.W + (size_t)j * K;
        else if (j < s1.jend) wrow = s1.W + (size_t)(j - s0.jend) * K;
        else if (j < s2.jend) wrow = s2.W + (size_t)(j - s1.jend) * K;
        wlds[jj][kk] = wrow ? wrow[kk] : 0.0f;
    }
    __syncthreads();
    {
        int n = t & 127, q = t >> 7;
        const int KQ = K/4;
        float acc[8];
        #pragma unroll
        for (int jj=0;jj<8;jj++) acc[jj]=0.0f;
        const float* xrow = X + (size_t)n*K + q*KQ;
        const float* wq = &wlds[0][0] + q*KQ;
        for (int kk=0; kk<KQ; ++kk){
            float xv = xrow[kk];
            #pragma unroll
            for (int jj=0;jj<8;jj++) acc[jj] = fmaf(xv, wq[jj*K+kk], acc[jj]);
        }
        #pragma unroll
        for (int jj=0;jj<8;jj++) red[q][n][jj] = acc[jj];
    }
    __syncthreads();
    if (t < 128){
        #pragma unroll
        for (int jj=0;jj<8;jj++){
            int j = jbase + jj;
            const Seg* sg = nullptr; int loc = 0;
            if (j < s0.jend){ sg=&s0; loc=j; }
            else if (j < s1.jend){ sg=&s1; loc=j-s0.jend; }
            else if (j < s2.jend){ sg=&s2; loc=j-s1.jend; }
            if (sg){
                float v = red[0][t][jj]+red[1][t][jj]+red[2][t][jj]+red[3][t][jj] + sg->B[loc];
                if (sg->act==1) v = sigm(v);
                sg->dst[(size_t)t * sg->stride + loc] = v;
            }
        }
    }
}

// Fused pass A+B, 2 syncthreads total. Per (n, 64-m chunk): scores -> sbuf;
// online-softmax partials (lmax, lsum, racc[128]) with C rows held in registers.
// knorm/beta computed in-wave (no prep kernel, no kl LDS stage).
__global__ __launch_bounds__(256) void passAB(const float* __restrict__ C, const float* __restrict__ kv,
                                              const float* __restrict__ braw,
                                              float* __restrict__ sbuf, float* __restrict__ racc,
                                              float* __restrict__ lmaxb, float* __restrict__ lsumb)
{
    __shared__ float rlds[4][128];
    __shared__ float wred[2][4];
    int t = threadIdx.x;
    int n = blockIdx.x >> 6;
    int mbase = (blockIdx.x & 63) << 6;
    int lane = t & 63, w = t >> 6;
    int s = t & 15, rowg = t >> 4;

    const float4* k4 = (const float4*)(kv + (size_t)n*DD);
    float4 ka = k4[s*2], kb = k4[s*2+1];
    float kq = ka.x*ka.x+ka.y*ka.y+ka.z*ka.z+ka.w*ka.w
             + kb.x*kb.x+kb.y*kb.y+kb.z*kb.z+kb.w*kb.w;
    #pragma unroll
    for (int off=1; off<16; off<<=1) kq += __shfl_xor(kq, off);
    float knorm = sqrtf(kq);
    float b = braw[n];
    float beta = 1.0f + fmaxf(b, 0.0f) + log1pf(expf(-fabsf(b)));

    const float4* C4 = (const float4*)C;
    float4 av[4], bw[4];
    float sval[4];
    #pragma unroll
    for (int it=0; it<4; ++it){
        int m = mbase + it*16 + rowg;
        size_t ridx = ((size_t)n*MM + m)*32 + s*2;
        float4 a = C4[ridx], b4 = C4[ridx+1];
        av[it] = a; bw[it] = b4;
        float dot = a.x*ka.x + a.y*ka.y + a.z*ka.z + a.w*ka.w
                  + b4.x*kb.x + b4.y*kb.y + b4.z*kb.z + b4.w*kb.w;
        float nr  = a.x*a.x + a.y*a.y + a.z*a.z + a.w*a.w
                  + b4.x*b4.x + b4.y*b4.y + b4.z*b4.z + b4.w*b4.w;
        #pragma unroll
        for (int off=1; off<16; off<<=1){
            dot += __shfl_xor(dot, off);
            nr  += __shfl_xor(nr, off);
        }
        float sv = beta * dot / fmaxf(sqrtf(nr)*knorm, EPSV);
        sval[it] = sv;
        if (s == 0) sbuf[(size_t)n*MM + m] = sv;
    }
    // wave max (rows duplicated across 16 lanes -> xor16/32 covers the wave's 4 row-groups)
    float lm = fmaxf(fmaxf(sval[0],sval[1]), fmaxf(sval[2],sval[3]));
    lm = fmaxf(lm, __shfl_xor(lm, 16));
    lm = fmaxf(lm, __shfl_xor(lm, 32));
    if (lane == 0) wred[0][w] = lm;
    __syncthreads();
    float lmax = fmaxf(fmaxf(wred[0][0], wred[0][1]), fmaxf(wred[0][2], wred[0][3]));

    float r8[8] = {0,0,0,0,0,0,0,0};
    float ps = 0.0f;
    #pragma unroll
    for (int it=0; it<4; ++it){
        float p = expf(sval[it] - lmax);
        ps += p;
        r8[0] = fmaf(p, av[it].x, r8[0]); r8[1] = fmaf(p, av[it].y, r8[1]);
        r8[2] = fmaf(p, av[it].z, r8[2]); r8[3] = fmaf(p, av[it].w, r8[3]);
        r8[4] = fmaf(p, bw[it].x, r8[4]); r8[5] = fmaf(p, bw[it].y, r8[5]);
        r8[6] = fmaf(p, bw[it].z, r8[6]); r8[7] = fmaf(p, bw[it].w, r8[7]);
    }
    ps += __shfl_xor(ps, 16); ps += __shfl_xor(ps, 32);
    #pragma unroll
    for (int j=0;j<8;j++){
        r8[j] += __shfl_xor(r8[j], 16);
        r8[j] += __shfl_xor(r8[j], 32);
    }
    if (lane < 16){
        #pragma unroll
        for (int j=0;j<8;j++) rlds[w][lane*8+j] = r8[j];
    }
    if (lane == 0) wred[1][w] = ps;
    __syncthreads();
    if (t < 128)
        racc[(size_t)blockIdx.x*128 + t] = rlds[0][t]+rlds[1][t]+rlds[2][t]+rlds[3][t];
    if (t == 0){
        lmaxb[blockIdx.x] = lmax;
        lsumb[blockIdx.x] = wred[1][0]+wred[1][1]+wred[1][2]+wred[1][3];
    }
}

// Fused per-n: combine -> r, gz; gi = r@W_ih^T; GRU gates -> h_o; e,v = h_o@{We,Wv}^T
__global__ __launch_bounds__(256) void mid(const float* __restrict__ racc, const float* __restrict__ lmaxb,
                                           const float* __restrict__ lsumb, const float* __restrict__ gh,
                                           const float* __restrict__ hp,
                                           const float* __restrict__ W_ih, const float* __restrict__ b_ih,
                                           const float* __restrict__ We, const float* __restrict__ be,
                                           const float* __restrict__ Wv, const float* __restrict__ bv,
                                           float* __restrict__ r_out, float* __restrict__ ho,
                                           float* __restrict__ gz, float* __restrict__ ebuf,
                                           float* __restrict__ vbuf)
{
    __shared__ float alpha[64];
    __shared__ float rsh[128];
    __shared__ float gish[1536];
    __shared__ float hosh[512];
    __shared__ float zsh;
    int n = blockIdx.x, t = threadIdx.x;
    if (t < 64){
        float lm = lmaxb[n*64 + t];
        float gm = lm;
        #pragma unroll
        for (int off=1; off<64; off<<=1) gm = fmaxf(gm, __shfl_xor(gm, off));
        float a = expf(lm - gm);
        alpha[t] = a;
        float zc = a * lsumb[n*64 + t];
        #pragma unroll
        for (int off=1; off<64; off<<=1) zc += __shfl_xor(zc, off);
        if (t == 0){ zsh = zc; gz[n] = gm; gz[128+n] = 1.0f/zc; }
    }
    __syncthreads();
    float invZ = 1.0f / zsh;
    if (t < 128){
        const float* rb = racc + (size_t)n*64*128 + t;
        float acc = 0.0f;
        #pragma unroll 8
        for (int c=0; c<64; c++) acc = fmaf(alpha[c], rb[c*128], acc);
        float rv = acc * invZ;
        rsh[t] = rv;
        r_out[n*DD + t] = rv;
    }
    __syncthreads();
    {
        const float4* r4 = (const float4*)rsh;
        #pragma unroll
        for (int u=0; u<6; u++){
            int j = t + 256*u;
            const float4* wr = (const float4*)(W_ih + (size_t)j*DD);
            float acc = b_ih[j];
            #pragma unroll 8
            for (int kk=0; kk<32; kk++){
                float4 ww = wr[kk], rr = r4[kk];
                acc = fmaf(ww.x, rr.x, fmaf(ww.y, rr.y, fmaf(ww.z, rr.z, fmaf(ww.w, rr.w, acc))));
            }
            gish[j] = acc;
        }
    }
    __syncthreads();
    {
        const float* ghr = gh + (size_t)n*1536;
        #pragma unroll
        for (int u=0; u<2; u++){
            int j = t + 256*u;
            float rg = sigm(gish[j] + ghr[j]);
            float z  = sigm(gish[512+j] + ghr[512+j]);
            float ng = tanhf(gish[1024+j] + rg*ghr[1024+j]);
            float h  = hp[(size_t)n*DHH + j];
            float hv = (1.0f - z)*ng + z*h;
            hosh[j] = hv;
            ho[(size_t)n*DHH + j] = hv;
        }
    }
    __syncthreads();
    {
        const float* Wrow = (t < 128) ? (We + (size_t)t*DHH) : (Wv + (size_t)(t-128)*DHH);
        float acc = (t < 128) ? be[t] : bv[t-128];
        const float4* w4 = (const float4*)Wrow;
        const float4* h4 = (const float4*)hosh;
        #pragma unroll 8
        for (int kk=0; kk<128; kk++){
            float4 ww = w4[kk], hh = h4[kk];
            acc = fmaf(ww.x, hh.x, fmaf(ww.y, hh.y, fmaf(ww.z, hh.z, fmaf(ww.w, hh.w, acc))));
        }
        if (t < 128) ebuf[n*DD + t] = sigm(acc);
        else         vbuf[n*DD + (t-128)] = acc;
    }
}

// Pass C: C_new = C*(1 - w*e) + w*v, w reconstructed from sbuf.
// REVERSED block order (L3 reuse of passAB's tail-resident C) + non-temporal stores.
__global__ __launch_bounds__(256) void passC(const float* __restrict__ C, const float* __restrict__ sbuf,
                                             const float* __restrict__ gz,
                                             const float* __restrict__ e, const float* __restrict__ v,
                                             float* __restrict__ Cn)
{
    __shared__ float wl[64];
    int t = threadIdx.x;
    int bid = (int)(gridDim.x - 1 - blockIdx.x);
    int n = bid >> 6, mbase = (bid & 63) << 6;
    if (t < 64){
        float gm = gz[n], iz = gz[128+n];
        wl[t] = expf(sbuf[(size_t)n*MM + mbase + t] - gm) * iz;
    }
    __syncthreads();
    int l = t & 31, q = t >> 5;
    f32x4 e4 = ((const f32x4*)(e + (size_t)n*DD))[l];
    f32x4 v4 = ((const f32x4*)(v + (size_t)n*DD))[l];
    const f32x4* C4 = (const f32x4*)C;
    f32x4* Cn4 = (f32x4*)Cn;
    #pragma unroll
    for (int it=0; it<8; ++it){
        int m = mbase + it*8 + q;
        float wm = wl[it*8 + q];
        size_t ridx = ((size_t)n*MM + m)*32 + l;
        f32x4 c = C4[ridx];
        f32x4 o;
        o.x = fmaf(wm, v4.x, c.x * (1.0f - wm*e4.x));
        o.y = fmaf(wm, v4.y, c.y * (1.0f - wm*e4.y));
        o.z = fmaf(wm, v4.z, c.z * (1.0f - wm*e4.z));
        o.w = fmaf(wm, v4.w, c.w * (1.0f - wm*e4.w));
        __builtin_nontemporal_store(o, &Cn4[ridx]);
    }
}

extern "C" void kernel_launch(void* const* d_in, const int* in_sizes, int n_in,
                              void* d_out, int out_size, void* d_ws, size_t ws_size,
                              hipStream_t stream) {
    const float* hp   = (const float*)d_in[0];
    const float* C    = (const float*)d_in[1];
    const float* Wk   = (const float*)d_in[2];
    const float* bk   = (const float*)d_in[3];
    const float* Wb   = (const float*)d_in[4];
    const float* bb   = (const float*)d_in[5];
    const float* We   = (const float*)d_in[6];
    const float* be   = (const float*)d_in[7];
    const float* Wv   = (const float*)d_in[8];
    const float* bv   = (const float*)d_in[9];
    const float* W_ih = (const float*)d_in[10];
    const float* b_ih = (const float*)d_in[11];
    const float* W_hh = (const float*)d_in[12];
    const float* b_hh = (const float*)d_in[13];

    float* out   = (float*)d_out;
    float* ho    = out + HO_OFF;
    float* Cn    = out + CN_OFF;
    float* k_out = out + K_OFF;
    float* r_out = out + R_OFF;

    // scratch inside C_new region (consumed before passC)
    float* racc  = out + RACC_OFF;
    float* lmaxb = out + LMAX_OFF;
    float* lsumb = out + LSUM_OFF;
    float* gh    = out + GH_OFF;
    float* braw  = out + BRAW_OFF;

    float* wsf  = (float*)d_ws;
    float* sbuf = wsf + S_WS;
    float* ebuf = wsf + E_WS;
    float* vbuf = wsf + V_WS;
    float* gz   = wsf + GZ_WS;

    // 1) k, gh, beta_pre (from h_o_prev, K=512)
    {
        Seg s0 = {128, Wk, bk, k_out, 128, 0};
        Seg s1 = {1664, W_hh, b_hh, gh, 1536, 0};
        Seg s2 = {1665, Wb, bb, braw, 1, 0};
        proj8<512><<<209, 512, 0, stream>>>(hp, s0, s1, s2);
    }
    // 2) fused scores + online-softmax partial r (knorm/beta in-wave)
    passAB<<<8192, 256, 0, stream>>>(C, k_out, braw, sbuf, racc, lmaxb, lsumb);
    // 3) combine + gi + gates + e,v  (one kernel, per-n blocks)
    mid<<<128, 256, 0, stream>>>(racc, lmaxb, lsumb, gh, hp, W_ih, b_ih,
                                 We, be, Wv, bv, r_out, ho, gz, ebuf, vbuf);
    // 4) C_new = C*(1 - w*e) + w*v  (reverse order + nt stores)
    passC<<<8192, 256, 0, stream>>>(C, sbuf, gz, ebuf, vbuf, Cn);
}